// Round 5
// baseline (4117.402 us; speedup 1.0000x reference)
//
#include <hip/hip_runtime.h>
#include <hip/hip_bf16.h>

#define B_ 256
#define S_ 2048
#define D_ 16
#define H_ 128

typedef unsigned int u32;
typedef unsigned short u16;
typedef _Float16 h2t __attribute__((ext_vector_type(2)));

// ---- output layout (flat f32): returns | volatility | hidden_h | hidden_c
#define RET0 ((size_t)0)
#define VOL0 ((size_t)524288)
#define HH0  ((size_t)1048576)
#define HC0  ((size_t)1114112)

__device__ __forceinline__ float fdot2(u32 a, u32 b, float c) {
    return __builtin_amdgcn_fdot2(__builtin_bit_cast(h2t, a),
                                  __builtin_bit_cast(h2t, b), c, false);
}
__device__ __forceinline__ u32 packh2(float a, float b) {
    h2t h; h[0] = (_Float16)a; h[1] = (_Float16)b;
    return __builtin_bit_cast(u32, h);
}
__device__ __forceinline__ float sigm(float x) {
    return __builtin_amdgcn_rcpf(1.f + __builtin_amdgcn_exp2f(-1.44269504f * x));
}
__device__ __forceinline__ float tanh_(float x) {
    return 2.f * __builtin_amdgcn_rcpf(1.f + __builtin_amdgcn_exp2f(-2.88539008f * x)) - 1.f;
}
__device__ __forceinline__ float softplus_(float x) {
    if (x > 20.f) return x;
    const float e = __builtin_amdgcn_exp2f(1.44269504f * x);
    return 0.69314718f * __builtin_amdgcn_logf(1.f + e);  // v_log_f32 is log2
}

// ===================== layer 0: fully scalar f32 ============================
// 512 threads: g = tid>>7 (gate), m = tid&127 (unit). Gates meet in LDS.
__global__ __launch_bounds__(512) void k_l0(
    const float* __restrict__ x, const float* __restrict__ Wih,
    const float* __restrict__ Whh, const float* __restrict__ bih,
    const float* __restrict__ bhh, u32* __restrict__ h1out,
    float* __restrict__ out)
{
    __shared__ float xs[512 * 16];    // 512-step x window, f32 (32KB)
    __shared__ float gates[4][128];   // gate pre-activations
    __shared__ float hf[128];         // h state, f32 scalars
    __shared__ u32 och[64 * 64];      // 64-step h1 pair staging (16KB)

    const int tid = threadIdx.x, b = blockIdx.x;
    const int g = tid >> 7, m = tid & 127, row = g * 128 + m;

    float wx[16], wh[128];
#pragma unroll
    for (int j = 0; j < 16; ++j) wx[j] = Wih[row * 16 + j];
#pragma unroll
    for (int j = 0; j < 128; ++j) wh[j] = Whh[row * 128 + j];
    const float bs = bih[row] + bhh[row];

    float c = 0.f;
    if (tid < 128) hf[tid] = 0.f;
    __syncthreads();

    const float* xb = x + (size_t)b * S_ * D_;
    for (int t = 0; t < S_; ++t) {
        if ((t & 511) == 0) {         // stage next 512-step x window
            for (int i = tid; i < 2048; i += 512) {
                const float4 v = *(const float4*)(xb + (size_t)t * 16 + i * 4);
                *(float4*)(&xs[i * 4]) = v;
            }
            __syncthreads();
        }
        // phase 1: every thread computes one gate pre-activation
        float a = bs;
        const float* xt = &xs[(t & 511) * 16];
#pragma unroll
        for (int j = 0; j < 16; ++j) a += wx[j] * xt[j];
#pragma unroll
        for (int j = 0; j < 128; ++j) a += wh[j] * hf[j];
        gates[g][m] = a;
        __syncthreads();
        // phase 2: unit threads combine gates
        if (tid < 128) {
            const float ig = sigm(gates[0][tid]);
            const float fg = sigm(gates[1][tid]);
            const float gc = tanh_(gates[2][tid]);
            const float og = sigm(gates[3][tid]);
            c = fg * c + ig * gc;
            const float h = og * tanh_(c);
            hf[tid] = h;
            if (t == S_ - 1) {
                out[HH0 + (size_t)b * H_ + tid] = h;
                out[HC0 + (size_t)b * H_ + tid] = c;
            }
        }
        __syncthreads();
        // phase 3: snapshot h1_t as f16 pairs
        if (tid < 64) och[(t & 63) * 64 + tid] = packh2(hf[2 * tid], hf[2 * tid + 1]);
        if ((t & 63) == 63) {         // flush 64 steps (uniform branch)
            __syncthreads();
            u32* dst = h1out + ((size_t)b * S_ + (t - 63)) * 64;
            *(uint4*)(dst + tid * 8)     = *(const uint4*)(&och[tid * 8]);
            *(uint4*)(dst + tid * 8 + 4) = *(const uint4*)(&och[tid * 8 + 4]);
        }
        __syncthreads();
    }
}

// ===================== layer 1: f16-pair dots, same dumb structure ==========
// h2 pairs overwrite consumed h1 rows in-place (ws stays 134MB).
__global__ __launch_bounds__(512) void k_l1(
    u32* __restrict__ hws,
    const float* __restrict__ Wih, const float* __restrict__ Whh,
    const float* __restrict__ bih, const float* __restrict__ bhh,
    float* __restrict__ out)
{
    __shared__ u32 h1w[128 * 64];     // 128-step h1 pair window (32KB)
    __shared__ float gates[4][128];
    __shared__ u32 hp[64];            // h2 state, f16 pairs
    __shared__ u32 och[64 * 64];      // h2 staging (16KB)

    const int tid = threadIdx.x, b = blockIdx.x;
    const int g = tid >> 7, m = tid & 127, row = g * 128 + m;

    u32 wi[64], wh[64];
#pragma unroll
    for (int j = 0; j < 64; ++j) {
        const float2 a = *(const float2*)(Wih + row * 128 + 2 * j);
        const float2 cc = *(const float2*)(Whh + row * 128 + 2 * j);
        wi[j] = packh2(a.x, a.y);
        wh[j] = packh2(cc.x, cc.y);
    }
    const float bs = bih[row] + bhh[row];

    float c = 0.f;
    if (tid < 64) hp[tid] = 0u;
    __syncthreads();

    u32* hb = hws + (size_t)b * S_ * 64;
    for (int t = 0; t < S_; ++t) {
        if ((t & 127) == 0) {         // stage 128-step h1 window
            for (int i = tid; i < 2048; i += 512)
                *(uint4*)(&h1w[i * 4]) = *(const uint4*)(hb + (size_t)t * 64 + i * 4);
            __syncthreads();
        }
        // phase 1
        float a = bs;
        const u32* h1t = &h1w[(t & 127) * 64];
#pragma unroll
        for (int j = 0; j < 64; ++j) a = fdot2(h1t[j], wi[j], a);
#pragma unroll
        for (int j = 0; j < 64; ++j) a = fdot2(hp[j], wh[j], a);
        gates[g][m] = a;
        __syncthreads();
        // phase 2
        if (tid < 128) {
            const float ig = sigm(gates[0][tid]);
            const float fg = sigm(gates[1][tid]);
            const float gc = tanh_(gates[2][tid]);
            const float og = sigm(gates[3][tid]);
            c = fg * c + ig * gc;
            const float h = og * tanh_(c);
            ((u16*)hp)[tid] = __builtin_bit_cast(unsigned short, (_Float16)h);
            if (t == S_ - 1) {
                out[HH0 + 32768 + (size_t)b * H_ + tid] = h;
                out[HC0 + 32768 + (size_t)b * H_ + tid] = c;
            }
        }
        __syncthreads();
        // phase 3: snapshot h2_t pairs
        if (tid < 64) och[(t & 63) * 64 + tid] = hp[tid];
        if ((t & 63) == 63) {
            __syncthreads();
            u32* dst = hb + (size_t)(t - 63) * 64;
            *(uint4*)(dst + tid * 8)     = *(const uint4*)(&och[tid * 8]);
            *(uint4*)(dst + tid * 8 + 4) = *(const uint4*)(&och[tid * 8 + 4]);
        }
        __syncthreads();
    }
}

// ===================== heads: parallel over (b,s) ===========================
__global__ __launch_bounds__(256) void k_heads(
    const u32* __restrict__ h2p,
    const float* __restrict__ Wr1, const float* __restrict__ br1,
    const float* __restrict__ Wr2, const float* __restrict__ br2,
    const float* __restrict__ Wv1, const float* __restrict__ bv1,
    const float* __restrict__ Wv2, const float* __restrict__ bv2,
    float* __restrict__ out)
{
    __shared__ u32 wr[64 * 64], wv[64 * 64];   // W1 pairs (16KB each)
    __shared__ float w2r[64], w2v[64], b1r[64], b1v[64];

    const int tid = threadIdx.x;
    for (int i = tid; i < 4096; i += 256) {
        wr[i] = packh2(Wr1[2 * i], Wr1[2 * i + 1]);
        wv[i] = packh2(Wv1[2 * i], Wv1[2 * i + 1]);
    }
    if (tid < 64) {
        w2r[tid] = Wr2[tid]; w2v[tid] = Wv2[tid];
        b1r[tid] = br1[tid]; b1v[tid] = bv1[tid];
    }
    __syncthreads();

    const size_t bs = (size_t)blockIdx.x * 256 + tid;   // (b,s) flat
    u32 hq[64];
    const u32* src = h2p + bs * 64;
#pragma unroll
    for (int j4 = 0; j4 < 16; ++j4) {
        const uint4 v = *(const uint4*)(src + j4 * 4);
        hq[j4 * 4] = v.x; hq[j4 * 4 + 1] = v.y; hq[j4 * 4 + 2] = v.z; hq[j4 * 4 + 3] = v.w;
    }
    float ret = br2[0], vol = bv2[0];
    for (int k = 0; k < 64; ++k) {
        float r = b1r[k], v = b1v[k];
#pragma unroll
        for (int j = 0; j < 64; ++j) r = fdot2(hq[j], wr[k * 64 + j], r);
#pragma unroll
        for (int j = 0; j < 64; ++j) v = fdot2(hq[j], wv[k * 64 + j], v);
        r = r > 0.f ? r : 0.01f * r;
        v = v > 0.f ? v : 0.01f * v;
        ret += r * w2r[k];
        vol += v * w2v[k];
    }
    out[RET0 + bs] = ret;
    out[VOL0 + bs] = softplus_(vol);
}

extern "C" void kernel_launch(void* const* d_in, const int* in_sizes, int n_in,
                              void* d_out, int out_size, void* d_ws, size_t ws_size,
                              hipStream_t stream) {
    (void)in_sizes; (void)n_in; (void)out_size; (void)ws_size;
    const float* x    = (const float*)d_in[0];
    const float* Wih0 = (const float*)d_in[1];
    const float* Whh0 = (const float*)d_in[2];
    const float* bih0 = (const float*)d_in[3];
    const float* bhh0 = (const float*)d_in[4];
    const float* Wih1 = (const float*)d_in[5];
    const float* Whh1 = (const float*)d_in[6];
    const float* bih1 = (const float*)d_in[7];
    const float* bhh1 = (const float*)d_in[8];
    const float* Wr1  = (const float*)d_in[9];
    const float* br1  = (const float*)d_in[10];
    const float* Wr2  = (const float*)d_in[11];
    const float* br2  = (const float*)d_in[12];
    const float* Wv1  = (const float*)d_in[13];
    const float* bv1  = (const float*)d_in[14];
    const float* Wv2  = (const float*)d_in[15];
    const float* bv2  = (const float*)d_in[16];
    u32* hws = (u32*)d_ws;            // 256*2048*64 u32 = 134MB (h1 then h2 in-place)
    float* out = (float*)d_out;

    k_l0<<<B_, 512, 0, stream>>>(x, Wih0, Whh0, bih0, bhh0, hws, out);
    k_l1<<<B_, 512, 0, stream>>>(hws, Wih1, Whh1, bih1, bhh1, out);
    k_heads<<<2048, 256, 0, stream>>>(hws, Wr1, br1, Wr2, br2, Wv1, bv1, Wv2, bv2, out);
}